// Round 2
// baseline (2245.446 us; speedup 1.0000x reference)
//
#include <hip/hip_runtime.h>
#include <hip/hip_fp16.h>

// LSTM B=256,T=512,IN=64,H=128,L=2 + FC. One block per batch element.
// 1024 threads = 512 gate rows x 2 K-halves. Per thread resident fp16 weights:
// whh0-half(32) + wih1-half(32) + whh1-half(32) = 96 VGPRs -> fits 128-cap
// (16 waves/CU). w_ih0 lives in LDS (padded). Layers software-pipelined:
// iteration t computes L0(t) and L1(t-1) sharing the h0(t-1) broadcast read.
// 2 barriers/step. Partner K-halves combine via shfl_xor(1) (DPP).

#define BB 256
#define TT 512
#define INN 64
#define HH 128
#define GG 512           // 4*H gate rows per layer
#define W0STRIDE 36      // f16x2 units per wih0 LDS row (144 B, 16B aligned, bank-rotating)

typedef _Float16 f16x2 __attribute__((ext_vector_type(2)));

__device__ __forceinline__ f16x2 cvt2(float a, float b) {
    f16x2 r; r.x = (_Float16)a; r.y = (_Float16)b; return r;
}

__device__ __forceinline__ float fdot2_(f16x2 a, f16x2 b, float c) {
#if __has_builtin(__builtin_amdgcn_fdot2)
    return __builtin_amdgcn_fdot2(a, b, c, false);
#else
    return c + (float)a.x * (float)b.x + (float)a.y * (float)b.y;
#endif
}

__device__ __forceinline__ float tanh_f(float x) {
    float e = __expf(2.0f * x);
    return 1.0f - 2.0f * __builtin_amdgcn_rcpf(e + 1.0f);
}

__global__ __launch_bounds__(1024, 4) void lstm_fused(
    const float* __restrict__ x,
    const float* __restrict__ w_ih0, const float* __restrict__ w_hh0,
    const float* __restrict__ b_ih0, const float* __restrict__ b_hh0,
    const float* __restrict__ w_ih1, const float* __restrict__ w_hh1,
    const float* __restrict__ b_ih1, const float* __restrict__ b_hh1,
    const float* __restrict__ fc_w, const float* __restrict__ fc_b,
    float* __restrict__ out)
{
    const int tid = threadIdx.x;
    const int b   = blockIdx.x;
    const int row = tid >> 1;   // gate row 0..511 (for both layers)
    const int s   = tid & 1;    // K-half

    __shared__ __align__(16) f16x2 wih0s[GG * W0STRIDE];  // 73728 B
    __shared__ __align__(16) f16x2 h0sh[HH / 2];
    __shared__ __align__(16) f16x2 h1sh[HH / 2];
    __shared__ __align__(16) f16x2 xsh[INN / 2];
    __shared__ float gl0[GG];
    __shared__ float gl1[GG];
    __shared__ float h1f[HH];

    // ---- per-thread resident weights (fp16 halves of rows) ----
    f16x2 whh0h[32], wih1h[32], whh1h[32];
    {
        const float4* p = (const float4*)(w_hh0 + row * HH + s * 64);
        #pragma unroll
        for (int k = 0; k < 16; ++k) {
            float4 v = p[k];
            whh0h[2 * k]     = cvt2(v.x, v.y);
            whh0h[2 * k + 1] = cvt2(v.z, v.w);
        }
    }
    {
        const float4* p = (const float4*)(w_ih1 + row * HH + s * 64);
        #pragma unroll
        for (int k = 0; k < 16; ++k) {
            float4 v = p[k];
            wih1h[2 * k]     = cvt2(v.x, v.y);
            wih1h[2 * k + 1] = cvt2(v.z, v.w);
        }
    }
    {
        const float4* p = (const float4*)(w_hh1 + row * HH + s * 64);
        #pragma unroll
        for (int k = 0; k < 16; ++k) {
            float4 v = p[k];
            whh1h[2 * k]     = cvt2(v.x, v.y);
            whh1h[2 * k + 1] = cvt2(v.z, v.w);
        }
    }
    // ---- w_ih0 -> LDS (fp16, padded rows) ----
    {
        const float4* p = (const float4*)w_ih0;  // 512*64 floats = 8192 float4
        #pragma unroll
        for (int q = 0; q < 8; ++q) {
            int idx = tid * 8 + q;
            float4 v = p[idx];
            int pu = idx * 2;            // f16x2 linear index over [512][32]
            int r = pu >> 5, c = pu & 31;
            wih0s[r * W0STRIDE + c]     = cvt2(v.x, v.y);
            wih0s[r * W0STRIDE + c + 1] = cvt2(v.z, v.w);
        }
    }
    const float mybias = (s == 0) ? (b_ih0[row] + b_hh0[row])
                                  : (b_ih1[row] + b_hh1[row]);

    if (tid < 64)        h0sh[tid] = cvt2(0.f, 0.f);
    else if (tid < 128)  h1sh[tid - 64] = cvt2(0.f, 0.f);
    else if (tid >= 256 && tid < 272) {
        int q = tid - 256;
        float4 v = ((const float4*)x)[(b * TT + 0) * 16 + q];
        xsh[2 * q]     = cvt2(v.x, v.y);
        xsh[2 * q + 1] = cvt2(v.z, v.w);
    }
    float c0 = 0.f, c1 = 0.f;
    __syncthreads();

    const f16x2* __restrict__ w0r = &wih0s[row * W0STRIDE + s * 16];
    const f16x2* __restrict__ h0p = &h0sh[s * 32];
    const f16x2* __restrict__ h1p = &h1sh[s * 32];
    const f16x2* __restrict__ xp  = &xsh[s * 16];

    #pragma unroll 1
    for (int t = 0; t <= TT; ++t) {
        // ---- dot phase: L0(t) and L1(t-1) partial preacts (this K-half) ----
        float a0 = 0.f, a1 = 0.f, p0 = 0.f, p1 = 0.f;
        #pragma unroll
        for (int j = 0; j < 16; j += 2) {          // x . wih0 (L0)
            a0 = fdot2_(xp[j],     w0r[j],     a0);
            a1 = fdot2_(xp[j + 1], w0r[j + 1], a1);
        }
        #pragma unroll
        for (int k = 0; k < 32; k += 2) {          // h0 . {whh0 (L0), wih1 (L1)}
            f16x2 ha = h0p[k], hb = h0p[k + 1];
            a0 = fdot2_(ha, whh0h[k],     a0);
            p0 = fdot2_(ha, wih1h[k],     p0);
            a1 = fdot2_(hb, whh0h[k + 1], a1);
            p1 = fdot2_(hb, wih1h[k + 1], p1);
        }
        #pragma unroll
        for (int k = 0; k < 32; k += 2) {          // h1 . whh1 (L1)
            p0 = fdot2_(h1p[k],     whh1h[k],     p0);
            p1 = fdot2_(h1p[k + 1], whh1h[k + 1], p1);
        }
        float l0 = a0 + a1; l0 += __shfl_xor(l0, 1, 64);
        float l1 = p0 + p1; l1 += __shfl_xor(l1, 1, 64);
        {
            float z = ((s == 0) ? l0 : l1) + mybias;
            bool isg = (row >= 256) & (row < 384);      // g-gate -> tanh
            float zz = isg ? 2.f * z : z;
            float e  = __expf(-zz);
            float sg = __builtin_amdgcn_rcpf(1.f + e);  // sigmoid(zz)
            float act = isg ? 2.f * sg - 1.f : sg;      // tanh via sigmoid
            if (s == 0) gl0[row] = act; else gl1[row] = act;
        }
        __syncthreads();  // B1

        // ---- update phase ----
        if (tid < 128) {                    // L0 state (valid for t < TT)
            if (t < TT) {
                float gi = gl0[tid], gf = gl0[tid + 128];
                float gg = gl0[tid + 256], go = gl0[tid + 384];
                c0 = gf * c0 + gi * gg;
                float hh = go * tanh_f(c0);
                ((_Float16*)h0sh)[tid] = (_Float16)hh;
            }
        } else if (tid < 256) {             // L1 state for time t-1 (t >= 1)
            if (t >= 1) {
                int j = tid - 128;
                float gi = gl1[j], gf = gl1[j + 128];
                float gg = gl1[j + 256], go = gl1[j + 384];
                c1 = gf * c1 + gi * gg;
                float hh = go * tanh_f(c1);
                ((_Float16*)h1sh)[j] = (_Float16)hh;
                if (t == TT) h1f[j] = hh;
            }
        } else if (tid < 272) {             // prefetch x(t+1)
            if (t + 1 < TT) {
                int q = tid - 256;
                float4 v = ((const float4*)x)[(b * TT + t + 1) * 16 + q];
                xsh[2 * q]     = cvt2(v.x, v.y);
                xsh[2 * q + 1] = cvt2(v.z, v.w);
            }
        }
        __syncthreads();  // B2
    }

    // ---- FC epilogue ----
    if (tid < 64) {
        float p = h1f[tid] * fc_w[tid] + h1f[tid + 64] * fc_w[tid + 64];
        #pragma unroll
        for (int off = 32; off > 0; off >>= 1) p += __shfl_down(p, off, 64);
        if (tid == 0) out[b] = p + fc_b[0];
    }
}

extern "C" void kernel_launch(void* const* d_in, const int* in_sizes, int n_in,
                              void* d_out, int out_size, void* d_ws, size_t ws_size,
                              hipStream_t stream) {
    const float* x     = (const float*)d_in[0];
    const float* w_ih0 = (const float*)d_in[1];
    const float* w_hh0 = (const float*)d_in[2];
    const float* b_ih0 = (const float*)d_in[3];
    const float* b_hh0 = (const float*)d_in[4];
    const float* w_ih1 = (const float*)d_in[5];
    const float* w_hh1 = (const float*)d_in[6];
    const float* b_ih1 = (const float*)d_in[7];
    const float* b_hh1 = (const float*)d_in[8];
    const float* fc_w  = (const float*)d_in[9];
    const float* fc_b  = (const float*)d_in[10];
    float* out = (float*)d_out;

    lstm_fused<<<dim3(BB), dim3(1024), 0, stream>>>(
        x, w_ih0, w_hh0, b_ih0, b_hh0, w_ih1, w_hh1, b_ih1, b_hh1,
        fc_w, fc_b, out);
}